// Round 1
// baseline (75.238 us; speedup 1.0000x reference)
//
#include <hip/hip_runtime.h>

// FuzzyLayer: batch=4096, in_dim=64, out_dim=64, n_rules=256, all f32.
// Phase A: W[n,r] = min_i trapmf(x[n,i], Antes[r,i,0..3])
// Phase B: out[n,j] = (sum_r num(w)) / (sum_r den(w) + 256*eps) / 3
//   num = c1*w + c2*w^2 + c3*w^3 ; den = d1*w + d2*w^2   (coeffs from Cons)

#define EPS_TRAP 1e-8f
#define EPS_F32  1.1920928955078125e-07f

constexpr int BATCH   = 4096;
constexpr int IN_DIM  = 64;
constexpr int OUT_DIM = 64;
constexpr int N_RULES = 256;

// ---------------- prep: reciprocals for trapmf + polynomial coefficients ----
__global__ __launch_bounds__(256) void prep_kernel(
    const float4* __restrict__ Antes,   // [N_RULES*IN_DIM]
    const float4* __restrict__ Cons,    // [N_RULES*OUT_DIM]
    float4* __restrict__ aPrep,         // [N_RULES*IN_DIM]: inv_ba, -a*inv_ba, -inv_dc, d*inv_dc
    float4* __restrict__ cPrep,         // [N_RULES*OUT_DIM]: c1,c2,c3,d1
    float*  __restrict__ dPrep)         // [N_RULES*OUT_DIM]: d2
{
    int t = blockIdx.x * 256 + threadIdx.x;     // 0..16383
    float4 q = Antes[t];
    float iba = 1.0f / (q.y - q.x + EPS_TRAP);
    float idc = 1.0f / (q.w - q.z + EPS_TRAP);
    aPrep[t] = make_float4(iba, -q.x * iba, -idc, q.w * idc);

    float4 c = Cons[t];
    float A = c.x, B = c.y, C = c.z, D = c.w;
    float c1 = 3.0f * (D * D - A * A);
    float c2 = 3.0f * (C * D - A * B) - c1;
    float c3 = (C - D + A - B) * (C - D - A + B);
    float d1 = 2.0f * (D - A);
    float d2 = C + A - D - B;
    cPrep[t] = make_float4(c1, c2, c3, d1);
    dPrep[t] = d2;
}

// ---------------- phase A: rule strengths W^T[r][n] ------------------------
// grid = 64 batch-blocks x 16 rule-blocks = 1024 blocks, 256 threads (4 waves)
// block: 64 batch rows (staged in padded LDS), 16 rules (4 per wave)
__global__ __launch_bounds__(256) void w_kernel(
    const float*  __restrict__ x,       // [BATCH][IN_DIM]
    const float4* __restrict__ aPrep,   // [N_RULES*IN_DIM]
    float* __restrict__ WT)             // [N_RULES][BATCH]
{
    __shared__ float xs[IN_DIM][65];    // [i][n_local], pad -> conflict-free

    int nblk = blockIdx.x & 63;
    int rb   = (blockIdx.x >> 6) * 16;
    int n0   = nblk * 64;

    // stage 64x64 x-tile, coalesced reads, padded writes
    for (int k = 0; k < 16; ++k) {
        int idx = threadIdx.x + k * 256;    // 0..4095
        int nl = idx >> 6, i = idx & 63;
        xs[i][nl] = x[(n0 + nl) * IN_DIM + i];
    }
    __syncthreads();

    int lane = threadIdx.x & 63;
    int wv   = threadIdx.x >> 6;

    for (int rr = 0; rr < 4; ++rr) {
        int r = rb + rr * 4 + wv;
        const float4* ap = aPrep + r * IN_DIM;
        float wmin = 1e30f;
        #pragma unroll 8
        for (int i = 0; i < IN_DIM; ++i) {
            float4 p = ap[i];               // wave-uniform -> broadcast load
            float xv = xs[i][lane];
            float rise = fmaf(xv, p.x, p.y);
            float fall = fmaf(xv, p.z, p.w);
            float y = fminf(rise, fall);
            y = fminf(fmaxf(y, 0.0f), 1.0f);    // med3 clamp
            wmin = fminf(wmin, y);
        }
        WT[r * BATCH + n0 + lane] = wmin;       // coalesced per wave
    }
}

// ---------------- phase B: rule combination --------------------------------
// grid = 256 blocks x 256 threads; wave = one batch row's 64 outputs,
// 4 rows per wave to amortize coefficient loads.
__global__ __launch_bounds__(256) void combine_kernel(
    const float*  __restrict__ WT,      // [N_RULES][BATCH]
    const float4* __restrict__ cPrep,   // [N_RULES*OUT_DIM]
    const float*  __restrict__ dPrep,   // [N_RULES*OUT_DIM]
    float* __restrict__ out)            // [BATCH][OUT_DIM]
{
    int lane = threadIdx.x & 63;        // = output dim j
    int wv   = threadIdx.x >> 6;
    int nbase = blockIdx.x * 16 + wv * 4;

    float num[4] = {0.f, 0.f, 0.f, 0.f};
    float den[4] = {0.f, 0.f, 0.f, 0.f};

    for (int r = 0; r < N_RULES; ++r) {
        float4 cp = cPrep[r * OUT_DIM + lane];  // coalesced
        float  d2 = dPrep[r * OUT_DIM + lane];
        #pragma unroll
        for (int k = 0; k < 4; ++k) {
            float w  = WT[r * BATCH + nbase + k];   // uniform -> broadcast, L1-hot
            float w2 = w * w;
            float w3 = w2 * w;
            num[k] = fmaf(cp.x, w,  num[k]);
            num[k] = fmaf(cp.y, w2, num[k]);
            num[k] = fmaf(cp.z, w3, num[k]);
            den[k] = fmaf(cp.w, w,  den[k]);
            den[k] = fmaf(d2,   w2, den[k]);
        }
    }
    #pragma unroll
    for (int k = 0; k < 4; ++k) {
        float ds = den[k] + 256.0f * EPS_F32;
        float ys = (ds != 0.0f) ? (num[k] / ds) : 0.0f;
        out[(nbase + k) * OUT_DIM + lane] = ys * (1.0f / 3.0f);
    }
}

// ---------------- fallback: fully fused, no workspace ----------------------
// grid = 512 blocks x 256 threads; block = 8 batch rows, all rules.
__global__ __launch_bounds__(256) void fused_kernel(
    const float*  __restrict__ x,
    const float4* __restrict__ Antes,
    const float4* __restrict__ Cons,
    float* __restrict__ out)
{
    __shared__ float xs[IN_DIM][9];     // [i][n_local]
    __shared__ float wl[N_RULES][9];    // [r][n_local]

    int n0 = blockIdx.x * 8;
    int t  = threadIdx.x;

    for (int k = 0; k < 2; ++k) {
        int idx = t * 2 + k;            // 0..511
        int nl = idx >> 6, i = idx & 63;
        xs[i][nl] = x[(n0 + nl) * IN_DIM + i];
    }
    __syncthreads();

    // phase A: thread t = rule t
    {
        float wmin[8];
        #pragma unroll
        for (int n = 0; n < 8; ++n) wmin[n] = 1e30f;
        const float4* ap = Antes + t * IN_DIM;
        for (int i = 0; i < IN_DIM; ++i) {
            float4 q = ap[i];
            float iba = 1.0f / (q.y - q.x + EPS_TRAP);
            float idc = 1.0f / (q.w - q.z + EPS_TRAP);
            float na = -q.x * iba, dq = q.w * idc;
            #pragma unroll
            for (int n = 0; n < 8; ++n) {
                float xv = xs[i][n];
                float y = fminf(fmaf(xv, iba, na), fmaf(xv, -idc, dq));
                y = fminf(fmaxf(y, 0.0f), 1.0f);
                wmin[n] = fminf(wmin[n], y);
            }
        }
        #pragma unroll
        for (int n = 0; n < 8; ++n) wl[t][n] = wmin[n];
    }
    __syncthreads();

    // phase B: wave wv handles rows n0+2*wv, n0+2*wv+1 ; lane = j
    int lane = t & 63, wv = t >> 6;
    float num0 = 0.f, den0 = 0.f, num1 = 0.f, den1 = 0.f;
    for (int r = 0; r < N_RULES; ++r) {
        float4 c = Cons[r * OUT_DIM + lane];
        float A = c.x, B = c.y, C = c.z, D = c.w;
        float c1 = 3.0f * (D * D - A * A);
        float c2 = 3.0f * (C * D - A * B) - c1;
        float c3 = (C - D + A - B) * (C - D - A + B);
        float d1 = 2.0f * (D - A);
        float d2 = C + A - D - B;
        float wa = wl[r][wv * 2], wb = wl[r][wv * 2 + 1];
        float wa2 = wa * wa, wa3 = wa2 * wa;
        float wb2 = wb * wb, wb3 = wb2 * wb;
        num0 = fmaf(c1, wa, num0); num0 = fmaf(c2, wa2, num0); num0 = fmaf(c3, wa3, num0);
        den0 = fmaf(d1, wa, den0); den0 = fmaf(d2, wa2, den0);
        num1 = fmaf(c1, wb, num1); num1 = fmaf(c2, wb2, num1); num1 = fmaf(c3, wb3, num1);
        den1 = fmaf(d1, wb, den1); den1 = fmaf(d2, wb2, den1);
    }
    den0 += 256.0f * EPS_F32;
    den1 += 256.0f * EPS_F32;
    float y0 = (den0 != 0.0f) ? num0 / den0 : 0.0f;
    float y1 = (den1 != 0.0f) ? num1 / den1 : 0.0f;
    out[(n0 + wv * 2) * OUT_DIM + lane]     = y0 * (1.0f / 3.0f);
    out[(n0 + wv * 2 + 1) * OUT_DIM + lane] = y1 * (1.0f / 3.0f);
}

extern "C" void kernel_launch(void* const* d_in, const int* in_sizes, int n_in,
                              void* d_out, int out_size, void* d_ws, size_t ws_size,
                              hipStream_t stream) {
    const float* x     = (const float*)d_in[0];
    const float* Antes = (const float*)d_in[1];
    const float* Cons  = (const float*)d_in[2];
    float* out = (float*)d_out;

    const size_t WT_BYTES = (size_t)N_RULES * BATCH * 4;           // 4 MiB
    const size_t AP_BYTES = (size_t)N_RULES * IN_DIM * 16;         // 256 KiB
    const size_t CP_BYTES = (size_t)N_RULES * OUT_DIM * 16;        // 256 KiB
    const size_t DP_BYTES = (size_t)N_RULES * OUT_DIM * 4;         // 64 KiB
    const size_t NEED = WT_BYTES + AP_BYTES + CP_BYTES + DP_BYTES;

    if (ws_size >= NEED) {
        char* wsp = (char*)d_ws;
        float*  WT    = (float*)wsp;
        float4* aPrep = (float4*)(wsp + WT_BYTES);
        float4* cPrep = (float4*)(wsp + WT_BYTES + AP_BYTES);
        float*  dPrep = (float*)(wsp + WT_BYTES + AP_BYTES + CP_BYTES);

        prep_kernel<<<64, 256, 0, stream>>>((const float4*)Antes, (const float4*)Cons,
                                            aPrep, cPrep, dPrep);
        w_kernel<<<1024, 256, 0, stream>>>(x, aPrep, WT);
        combine_kernel<<<256, 256, 0, stream>>>(WT, cPrep, dPrep, out);
    } else {
        fused_kernel<<<512, 256, 0, stream>>>(x, (const float4*)Antes,
                                              (const float4*)Cons, out);
    }
}

// Round 2
// 53.330 us; speedup vs baseline: 1.4108x; 1.4108x over previous
//
#include <hip/hip_runtime.h>

// FuzzyLayer: batch=4096, in_dim=64, out_dim=64, n_rules=256, f32.
// Phase A: W[r][n] = clamp(min_i min((x-a)iba, (x-d)nidc), 0, 1)
// Phase B (Horner): num += w*(c1 + w*(c2 + w*c3)); den += w*(d1 + w*d2)
//   out = (num_sum / (den_sum + 256*eps)) / 3
// Rules split 4-way across waves -> partial planes -> finalize.

#define EPS_TRAP 1e-8f
#define EPS_F32  1.1920928955078125e-07f

constexpr int BATCH   = 4096;
constexpr int IN_DIM  = 64;
constexpr int OUT_DIM = 64;
constexpr int N_RULES = 256;
constexpr int SPLITS  = 4;     // rule-splits (64 rules per wave)
constexpr int ROWS    = 8;     // batch rows per wave in combine

// ---------------- prep: trapmf params + Horner coefficients ----------------
__global__ __launch_bounds__(256) void prep_kernel(
    const float4* __restrict__ Antes,   // [N_RULES*IN_DIM]
    const float4* __restrict__ Cons,    // [N_RULES*OUT_DIM]
    float4* __restrict__ aPrep,         // (a, 1/(b-a+e), d, -1/(d-c+e))
    float4* __restrict__ cPrep,         // (c1, c2, c3, d1)
    float*  __restrict__ dPrep)         // d2
{
    int t = blockIdx.x * 256 + threadIdx.x;     // 0..16383
    float4 q = Antes[t];
    float iba  =  1.0f / (q.y - q.x + EPS_TRAP);
    float nidc = -1.0f / (q.w - q.z + EPS_TRAP);
    aPrep[t] = make_float4(q.x, iba, q.w, nidc);

    float4 c = Cons[t];
    float A = c.x, B = c.y, C = c.z, D = c.w;
    float c1 = 3.0f * (D * D - A * A);
    float c2 = 3.0f * (C * D - A * B) - c1;
    float c3 = (C - D + A - B) * (C - D - A + B);
    float d1 = 2.0f * (D - A);
    float d2 = C + A - D - B;
    cPrep[t] = make_float4(c1, c2, c3, d1);
    dPrep[t] = d2;
}

// ---------------- phase A: W[r][n] ----------------------------------------
// grid = 64 batch-blocks x 16 rule-groups; block = 64 rows x 16 rules.
// Rule params are wave-uniform (readfirstlane) -> scalar loads; x in LDS.
__global__ __launch_bounds__(256) void w_kernel(
    const float*  __restrict__ x,       // [BATCH][IN_DIM]
    const float4* __restrict__ aPrep,   // [N_RULES][IN_DIM]
    float* __restrict__ W)              // [N_RULES][BATCH]
{
    __shared__ float xs[IN_DIM][65];    // [i][n_local], padded

    int tid  = threadIdx.x;
    int nblk = blockIdx.x & 63;
    int rb   = (blockIdx.x >> 6) * 16;
    int n0   = nblk * 64;

    // stage 64x64 x-tile: float4 global loads, padded LDS writes
    #pragma unroll
    for (int k = 0; k < 4; ++k) {
        int flat = tid + k * 256;           // 0..1023
        int nl = flat >> 4;
        int i4 = (flat & 15) * 4;
        float4 v = *reinterpret_cast<const float4*>(x + (n0 + nl) * IN_DIM + i4);
        xs[i4 + 0][nl] = v.x;
        xs[i4 + 1][nl] = v.y;
        xs[i4 + 2][nl] = v.z;
        xs[i4 + 3][nl] = v.w;
    }
    __syncthreads();

    int lane = tid & 63;
    int wvu  = __builtin_amdgcn_readfirstlane(tid >> 6);    // force SGPR
    int r0   = rb + wvu * 4;                                 // 4 contiguous rules

    const float4* __restrict__ ap = aPrep + r0 * IN_DIM;

    float wmin[4] = {1e30f, 1e30f, 1e30f, 1e30f};
    #pragma unroll 4
    for (int i = 0; i < IN_DIM; ++i) {
        float xv = xs[i][lane];
        #pragma unroll
        for (int rr = 0; rr < 4; ++rr) {
            float4 p = ap[rr * IN_DIM + i];     // uniform -> s_load
            float rise = (xv - p.x) * p.y;
            float fall = (xv - p.z) * p.w;
            wmin[rr] = fminf(wmin[rr], fminf(rise, fall));  // v_min3
        }
    }
    #pragma unroll
    for (int rr = 0; rr < 4; ++rr) {
        float w = fminf(fmaxf(wmin[rr], 0.0f), 1.0f);       // clamp once
        W[(r0 + rr) * BATCH + n0 + lane] = w;
    }
}

// ---------------- phase B: partial rule combination ------------------------
// grid = 512 blocks x 256 thr; wave wv = rule-split wv, 8 rows, lane = j.
// 2048 waves = 2 waves/SIMD; w's are wave-uniform scalar loads.
__global__ __launch_bounds__(256) void combine_kernel(
    const float*  __restrict__ W,       // [N_RULES][BATCH]
    const float4* __restrict__ cPrep,   // [N_RULES][OUT_DIM]
    const float*  __restrict__ dPrep,   // [N_RULES][OUT_DIM]
    float* __restrict__ partN,          // [SPLITS][BATCH][OUT_DIM]
    float* __restrict__ partD)          // [SPLITS][BATCH][OUT_DIM]
{
    int tid   = threadIdx.x;
    int lane  = tid & 63;                                   // output dim j
    int wvu   = __builtin_amdgcn_readfirstlane(tid >> 6);   // rule split
    int nbase = blockIdx.x * ROWS;
    int r0    = wvu * (N_RULES / SPLITS);

    float num[ROWS], den[ROWS];
    #pragma unroll
    for (int k = 0; k < ROWS; ++k) { num[k] = 0.0f; den[k] = 0.0f; }

    #pragma unroll 2
    for (int r = r0; r < r0 + N_RULES / SPLITS; ++r) {
        float4 cp = cPrep[r * OUT_DIM + lane];      // coalesced b128
        float  d2 = dPrep[r * OUT_DIM + lane];      // coalesced b32
        const float* __restrict__ wp = W + r * BATCH + nbase;   // uniform
        float wv8[ROWS];
        #pragma unroll
        for (int k = 0; k < ROWS; ++k) wv8[k] = wp[k];          // s_load x8
        #pragma unroll
        for (int k = 0; k < ROWS; ++k) {
            float w = wv8[k];
            float tn = fmaf(cp.z, w, cp.y);         // c3*w + c2
            tn = fmaf(tn, w, cp.x);                 // (.)*w + c1
            num[k] = fmaf(tn, w, num[k]);           // += (.)*w
            float td = fmaf(d2, w, cp.w);           // d2*w + d1
            den[k] = fmaf(td, w, den[k]);           // += (.)*w
        }
    }
    #pragma unroll
    for (int k = 0; k < ROWS; ++k) {
        int e = (nbase + k) * OUT_DIM + lane;
        partN[wvu * BATCH * OUT_DIM + e] = num[k];
        partD[wvu * BATCH * OUT_DIM + e] = den[k];
    }
}

// ---------------- finalize: sum splits, divide -----------------------------
__global__ __launch_bounds__(256) void finalize_kernel(
    const float* __restrict__ partN,
    const float* __restrict__ partD,
    float* __restrict__ out)
{
    int e = blockIdx.x * 256 + threadIdx.x;     // 0..262143
    float n = 0.0f, d = 0.0f;
    #pragma unroll
    for (int s = 0; s < SPLITS; ++s) {
        n += partN[s * BATCH * OUT_DIM + e];
        d += partD[s * BATCH * OUT_DIM + e];
    }
    d += (float)N_RULES * EPS_F32;
    out[e] = (d != 0.0f) ? (n / d) * (1.0f / 3.0f) : 0.0f;
}

// ---------------- fallback: fully fused, no workspace (known-correct) ------
__global__ __launch_bounds__(256) void fused_kernel(
    const float*  __restrict__ x,
    const float4* __restrict__ Antes,
    const float4* __restrict__ Cons,
    float* __restrict__ out)
{
    __shared__ float xs[IN_DIM][9];
    __shared__ float wl[N_RULES][9];

    int n0 = blockIdx.x * 8;
    int t  = threadIdx.x;

    for (int k = 0; k < 2; ++k) {
        int idx = t * 2 + k;
        int nl = idx >> 6, i = idx & 63;
        xs[i][nl] = x[(n0 + nl) * IN_DIM + i];
    }
    __syncthreads();

    {
        float wmin[8];
        #pragma unroll
        for (int n = 0; n < 8; ++n) wmin[n] = 1e30f;
        const float4* ap = Antes + t * IN_DIM;
        for (int i = 0; i < IN_DIM; ++i) {
            float4 q = ap[i];
            float iba = 1.0f / (q.y - q.x + EPS_TRAP);
            float idc = 1.0f / (q.w - q.z + EPS_TRAP);
            float na = -q.x * iba, dq = q.w * idc;
            #pragma unroll
            for (int n = 0; n < 8; ++n) {
                float xv = xs[i][n];
                float y = fminf(fmaf(xv, iba, na), fmaf(xv, -idc, dq));
                y = fminf(fmaxf(y, 0.0f), 1.0f);
                wmin[n] = fminf(wmin[n], y);
            }
        }
        #pragma unroll
        for (int n = 0; n < 8; ++n) wl[t][n] = wmin[n];
    }
    __syncthreads();

    int lane = t & 63, wv = t >> 6;
    float num0 = 0.f, den0 = 0.f, num1 = 0.f, den1 = 0.f;
    for (int r = 0; r < N_RULES; ++r) {
        float4 c = Cons[r * OUT_DIM + lane];
        float A = c.x, B = c.y, C = c.z, D = c.w;
        float c1 = 3.0f * (D * D - A * A);
        float c2 = 3.0f * (C * D - A * B) - c1;
        float c3 = (C - D + A - B) * (C - D - A + B);
        float d1 = 2.0f * (D - A);
        float d2 = C + A - D - B;
        float wa = wl[r][wv * 2], wb = wl[r][wv * 2 + 1];
        float wa2 = wa * wa, wa3 = wa2 * wa;
        float wb2 = wb * wb, wb3 = wb2 * wb;
        num0 = fmaf(c1, wa, num0); num0 = fmaf(c2, wa2, num0); num0 = fmaf(c3, wa3, num0);
        den0 = fmaf(d1, wa, den0); den0 = fmaf(d2, wa2, den0);
        num1 = fmaf(c1, wb, num1); num1 = fmaf(c2, wb2, num1); num1 = fmaf(c3, wb3, num1);
        den1 = fmaf(d1, wb, den1); den1 = fmaf(d2, wb2, den1);
    }
    den0 += 256.0f * EPS_F32;
    den1 += 256.0f * EPS_F32;
    float y0 = (den0 != 0.0f) ? num0 / den0 : 0.0f;
    float y1 = (den1 != 0.0f) ? num1 / den1 : 0.0f;
    out[(n0 + wv * 2) * OUT_DIM + lane]     = y0 * (1.0f / 3.0f);
    out[(n0 + wv * 2 + 1) * OUT_DIM + lane] = y1 * (1.0f / 3.0f);
}

extern "C" void kernel_launch(void* const* d_in, const int* in_sizes, int n_in,
                              void* d_out, int out_size, void* d_ws, size_t ws_size,
                              hipStream_t stream) {
    const float* x     = (const float*)d_in[0];
    const float* Antes = (const float*)d_in[1];
    const float* Cons  = (const float*)d_in[2];
    float* out = (float*)d_out;

    const size_t W_BYTES  = (size_t)N_RULES * BATCH * 4;            // 4 MiB
    const size_t AP_BYTES = (size_t)N_RULES * IN_DIM * 16;          // 256 KiB
    const size_t CP_BYTES = (size_t)N_RULES * OUT_DIM * 16;         // 256 KiB
    const size_t DP_BYTES = (size_t)N_RULES * OUT_DIM * 4;          // 64 KiB
    const size_t PP_BYTES = (size_t)SPLITS * BATCH * OUT_DIM * 4;   // 4 MiB each
    const size_t NEED = W_BYTES + AP_BYTES + CP_BYTES + DP_BYTES + 2 * PP_BYTES;

    if (ws_size >= NEED) {
        char* p = (char*)d_ws;
        float*  Wp    = (float*)p;                    p += W_BYTES;
        float4* aPrep = (float4*)p;                   p += AP_BYTES;
        float4* cPrep = (float4*)p;                   p += CP_BYTES;
        float*  dPrep = (float*)p;                    p += DP_BYTES;
        float*  partN = (float*)p;                    p += PP_BYTES;
        float*  partD = (float*)p;

        prep_kernel<<<64, 256, 0, stream>>>((const float4*)Antes, (const float4*)Cons,
                                            aPrep, cPrep, dPrep);
        w_kernel<<<1024, 256, 0, stream>>>(x, aPrep, Wp);
        combine_kernel<<<512, 256, 0, stream>>>(Wp, cPrep, dPrep, partN, partD);
        finalize_kernel<<<1024, 256, 0, stream>>>(partN, partD, out);
    } else {
        fused_kernel<<<512, 256, 0, stream>>>(x, (const float4*)Antes,
                                              (const float4*)Cons, out);
    }
}

// Round 3
// 18.655 us; speedup vs baseline: 4.0330x; 2.8587x over previous
//
#include <hip/hip_runtime.h>

// FuzzyLayer: batch=4096, in_dim=64, out_dim=64, n_rules=256, f32.
// Key structural fact: w[n,r] = min_i memb_i; each memb>0 w.p. ~0.6 =>
// P(w>0) ~ 0.6^64 ~ 1e-14, and a rule with w==0 contributes EXACTLY 0 to
// both num and den (every term has a factor of w). So:
//  - phase A: early-exit the dim loop once all lane-minima <= 0 (exact),
//    and emit per-(64-row-block, 16-rule-group) fired bitmasks.
//  - phase B: flag-gated; all-zero blocks write zeros directly (exact).

#define EPS_TRAP 1e-8f
#define EPS_F32  1.1920928955078125e-07f

constexpr int BATCH   = 4096;
constexpr int IN_DIM  = 64;
constexpr int OUT_DIM = 64;
constexpr int N_RULES = 256;

// ---------------- prep: trapmf params -------------------------------------
// aPrep[r][i] = (a, 1/(b-a+eps), d, -1/(d-c+eps))
__global__ __launch_bounds__(256) void prep_kernel(
    const float4* __restrict__ Antes, float4* __restrict__ aPrep)
{
    int t = blockIdx.x * 256 + threadIdx.x;     // 0..16383
    float4 q = Antes[t];
    aPrep[t] = make_float4(q.x, 1.0f / (q.y - q.x + EPS_TRAP),
                           q.w, -1.0f / (q.w - q.z + EPS_TRAP));
}

// ---------------- phase A: W[r][n] + fired flags ---------------------------
// grid = 64 batch-blocks x 16 rule-groups = 1024 blocks, 256 thr (4 waves).
// wave = 4 rules x 64 rows; params via wave-uniform s_load; x in padded LDS.
// Early-exit: check every 8 dims whether any lane-minimum is still > 0.
__global__ __launch_bounds__(256) void w_kernel(
    const float*  __restrict__ x,       // [BATCH][IN_DIM]
    const float4* __restrict__ aPrep,   // [N_RULES][IN_DIM]
    float* __restrict__ W,              // [N_RULES][BATCH]
    unsigned* __restrict__ flags)       // [64][16]: bit lr = rule rgrp*16+lr fired
{
    __shared__ float xs[IN_DIM][65];    // padded -> conflict-free
    __shared__ unsigned fl[4];

    int tid  = threadIdx.x;
    int nblk = blockIdx.x & 63;
    int rgrp = blockIdx.x >> 6;         // 0..15
    int n0   = nblk * 64;

    // stage 64x64 x-tile: float4 global loads, padded LDS writes
    #pragma unroll
    for (int k = 0; k < 4; ++k) {
        int flat = tid + k * 256;       // 0..1023 float4s
        int nl = flat >> 4;
        int i4 = (flat & 15) * 4;
        float4 v = *reinterpret_cast<const float4*>(x + (n0 + nl) * IN_DIM + i4);
        xs[i4 + 0][nl] = v.x;
        xs[i4 + 1][nl] = v.y;
        xs[i4 + 2][nl] = v.z;
        xs[i4 + 3][nl] = v.w;
    }
    __syncthreads();

    int lane = tid & 63;
    int wvu  = __builtin_amdgcn_readfirstlane(tid >> 6);
    int r0   = rgrp * 16 + wvu * 4;

    const float4* __restrict__ ap = aPrep + r0 * IN_DIM;

    float wmin[4] = {1e30f, 1e30f, 1e30f, 1e30f};
    for (int ib = 0; ib < IN_DIM; ib += 8) {
        #pragma unroll
        for (int io = 0; io < 8; ++io) {
            int i = ib + io;
            float xv = xs[i][lane];
            #pragma unroll
            for (int rr = 0; rr < 4; ++rr) {
                float4 p = ap[rr * IN_DIM + i];     // uniform -> s_load
                float rise = (xv - p.x) * p.y;
                float fall = (xv - p.z) * p.w;
                wmin[rr] = fminf(wmin[rr], fminf(rise, fall));
            }
        }
        // exact early-exit: min is non-increasing; once <=0 final w is 0
        float m = fmaxf(fmaxf(wmin[0], wmin[1]), fmaxf(wmin[2], wmin[3]));
        if (!__any(m > 0.0f)) break;
    }

    unsigned bits = 0;
    #pragma unroll
    for (int rr = 0; rr < 4; ++rr) {
        float w = fminf(fmaxf(wmin[rr], 0.0f), 1.0f);
        W[(r0 + rr) * BATCH + n0 + lane] = w;
        if (__any(wmin[rr] > 0.0f)) bits |= 1u << (wvu * 4 + rr);
    }
    if (lane == 0) fl[wvu] = bits;
    __syncthreads();
    if (tid == 0) flags[nblk * 16 + rgrp] = fl[0] | fl[1] | fl[2] | fl[3];
}

// ---------------- phase B: flag-gated combine + in-block reduce ------------
// grid = 512 blocks x 512 thr (8 waves). Block owns 8 batch rows; wave wv
// owns rules wv*32..wv*32+31 (= flag groups 2wv, 2wv+1); lane = out dim j.
__global__ __launch_bounds__(512) void combine_kernel(
    const float*  __restrict__ W,       // [N_RULES][BATCH]
    const float4* __restrict__ Cons,    // [N_RULES][OUT_DIM]
    const unsigned* __restrict__ flags, // [64][16]
    float* __restrict__ out)            // [BATCH][OUT_DIM]
{
    __shared__ float lN[8][8][64];
    __shared__ float lD[8][8][64];
    __shared__ unsigned anyf[8];

    int tid   = threadIdx.x;
    int lane  = tid & 63;
    int wv    = __builtin_amdgcn_readfirstlane(tid >> 6);   // 0..7 rule split
    int nbase = blockIdx.x * 8;
    int nblk  = blockIdx.x >> 3;        // 64-row block index

    unsigned m0 = flags[nblk * 16 + wv * 2];
    unsigned m1 = flags[nblk * 16 + wv * 2 + 1];
    if (lane == 0) anyf[wv] = m0 | m1;
    __syncthreads();

    unsigned blockAny = anyf[0] | anyf[1] | anyf[2] | anyf[3] |
                        anyf[4] | anyf[5] | anyf[6] | anyf[7];
    if (blockAny == 0u) {
        // all 256 rules dead for these 64 rows: num=0, den=256*eps -> out=0
        out[nbase * OUT_DIM + tid] = 0.0f;
        return;
    }

    unsigned long long mask = (unsigned long long)m0 |
                              ((unsigned long long)m1 << 16);
    int rbase = wv * 32;

    float num[8], den[8];
    #pragma unroll
    for (int k = 0; k < 8; ++k) { num[k] = 0.0f; den[k] = 0.0f; }

    while (mask) {                      // wave-uniform sparse rule loop
        int lr = __ffsll(mask) - 1;
        mask &= mask - 1;
        int r = rbase + lr;

        float4 c = Cons[r * OUT_DIM + lane];    // coalesced b128
        float A = c.x, B = c.y, C = c.z, D = c.w;
        float c1 = 3.0f * (D * D - A * A);
        float c2 = 3.0f * (C * D - A * B) - c1;
        float c3 = (C - D + A - B) * (C - D - A + B);
        float d1 = 2.0f * (D - A);
        float d2 = C + A - D - B;

        const float* __restrict__ wp = W + r * BATCH + nbase;   // uniform
        #pragma unroll
        for (int k = 0; k < 8; ++k) {
            float w = wp[k];                    // s_load
            float tn = fmaf(fmaf(c3, w, c2), w, c1);
            num[k] = fmaf(tn, w, num[k]);
            den[k] = fmaf(fmaf(d2, w, d1), w, den[k]);
        }
    }

    #pragma unroll
    for (int k = 0; k < 8; ++k) { lN[wv][k][lane] = num[k]; lD[wv][k][lane] = den[k]; }
    __syncthreads();

    int row = tid >> 6;                 // 0..7
    float n = 0.0f, d = 0.0f;
    #pragma unroll
    for (int s = 0; s < 8; ++s) { n += lN[s][row][lane]; d += lD[s][row][lane]; }
    d += (float)N_RULES * EPS_F32;
    out[(nbase + row) * OUT_DIM + lane] = (d != 0.0f) ? (n / d) * (1.0f / 3.0f) : 0.0f;
}

// ---------------- fallback: fully fused, no workspace (known-correct) ------
__global__ __launch_bounds__(256) void fused_kernel(
    const float*  __restrict__ x,
    const float4* __restrict__ Antes,
    const float4* __restrict__ Cons,
    float* __restrict__ out)
{
    __shared__ float xs[IN_DIM][9];
    __shared__ float wl[N_RULES][9];

    int n0 = blockIdx.x * 8;
    int t  = threadIdx.x;

    for (int k = 0; k < 2; ++k) {
        int idx = t * 2 + k;
        int nl = idx >> 6, i = idx & 63;
        xs[i][nl] = x[(n0 + nl) * IN_DIM + i];
    }
    __syncthreads();

    {
        float wmin[8];
        #pragma unroll
        for (int n = 0; n < 8; ++n) wmin[n] = 1e30f;
        const float4* ap = Antes + t * IN_DIM;
        for (int i = 0; i < IN_DIM; ++i) {
            float4 q = ap[i];
            float iba = 1.0f / (q.y - q.x + EPS_TRAP);
            float idc = 1.0f / (q.w - q.z + EPS_TRAP);
            float na = -q.x * iba, dq = q.w * idc;
            #pragma unroll
            for (int n = 0; n < 8; ++n) {
                float xv = xs[i][n];
                float y = fminf(fmaf(xv, iba, na), fmaf(xv, -idc, dq));
                y = fminf(fmaxf(y, 0.0f), 1.0f);
                wmin[n] = fminf(wmin[n], y);
            }
        }
        #pragma unroll
        for (int n = 0; n < 8; ++n) wl[t][n] = wmin[n];
    }
    __syncthreads();

    int lane = t & 63, wv = t >> 6;
    float num0 = 0.f, den0 = 0.f, num1 = 0.f, den1 = 0.f;
    for (int r = 0; r < N_RULES; ++r) {
        float4 c = Cons[r * OUT_DIM + lane];
        float A = c.x, B = c.y, C = c.z, D = c.w;
        float c1 = 3.0f * (D * D - A * A);
        float c2 = 3.0f * (C * D - A * B) - c1;
        float c3 = (C - D + A - B) * (C - D - A + B);
        float d1 = 2.0f * (D - A);
        float d2 = C + A - D - B;
        float wa = wl[r][wv * 2], wb = wl[r][wv * 2 + 1];
        float wa2 = wa * wa, wa3 = wa2 * wa;
        float wb2 = wb * wb, wb3 = wb2 * wb;
        num0 = fmaf(c1, wa, num0); num0 = fmaf(c2, wa2, num0); num0 = fmaf(c3, wa3, num0);
        den0 = fmaf(d1, wa, den0); den0 = fmaf(d2, wa2, den0);
        num1 = fmaf(c1, wb, num1); num1 = fmaf(c2, wb2, num1); num1 = fmaf(c3, wb3, num1);
        den1 = fmaf(d1, wb, den1); den1 = fmaf(d2, wb2, den1);
    }
    den0 += 256.0f * EPS_F32;
    den1 += 256.0f * EPS_F32;
    float y0 = (den0 != 0.0f) ? num0 / den0 : 0.0f;
    float y1 = (den1 != 0.0f) ? num1 / den1 : 0.0f;
    out[(n0 + wv * 2) * OUT_DIM + lane]     = y0 * (1.0f / 3.0f);
    out[(n0 + wv * 2 + 1) * OUT_DIM + lane] = y1 * (1.0f / 3.0f);
}

extern "C" void kernel_launch(void* const* d_in, const int* in_sizes, int n_in,
                              void* d_out, int out_size, void* d_ws, size_t ws_size,
                              hipStream_t stream) {
    const float* x     = (const float*)d_in[0];
    const float* Antes = (const float*)d_in[1];
    const float* Cons  = (const float*)d_in[2];
    float* out = (float*)d_out;

    const size_t W_BYTES  = (size_t)N_RULES * BATCH * 4;    // 4 MiB
    const size_t AP_BYTES = (size_t)N_RULES * IN_DIM * 16;  // 256 KiB
    const size_t FL_BYTES = 64 * 16 * sizeof(unsigned);     // 4 KiB
    const size_t NEED = W_BYTES + AP_BYTES + FL_BYTES;

    if (ws_size >= NEED) {
        char* p = (char*)d_ws;
        float*    Wp    = (float*)p;      p += W_BYTES;
        float4*   aPrep = (float4*)p;     p += AP_BYTES;
        unsigned* flags = (unsigned*)p;

        prep_kernel<<<64, 256, 0, stream>>>((const float4*)Antes, aPrep);
        w_kernel<<<1024, 256, 0, stream>>>(x, aPrep, Wp, flags);
        combine_kernel<<<512, 512, 0, stream>>>(Wp, (const float4*)Cons, flags, out);
    } else {
        fused_kernel<<<512, 256, 0, stream>>>(x, (const float4*)Antes,
                                              (const float4*)Cons, out);
    }
}

// Round 4
// 14.902 us; speedup vs baseline: 5.0487x; 1.2519x over previous
//
#include <hip/hip_runtime.h>

// FuzzyLayer: batch=4096, in_dim=64, out_dim=64, n_rules=256, f32.
// Exact sparsity: w[n,r] = min_i trapmf > 0 with p ~ 1e-14, and w==0 rules
// contribute EXACTLY 0 to num and den. Sign test needs no reciprocals:
//   w>0  <=>  min_i min(x-a, d-x) > 0     (scale factors are positive)
// So phase A = 3 VALU ops per (chain,dim) with early exit; exact w (with
// divisions) is computed+stored ONLY for fired (rule, row-block) pairs.
// Phase B is flag-gated: all-dead blocks write zeros directly (exact).

#define EPS_TRAP 1e-8f
#define EPS_F32  1.1920928955078125e-07f

constexpr int BATCH   = 4096;
constexpr int IN_DIM  = 64;
constexpr int OUT_DIM = 64;
constexpr int N_RULES = 256;

// ---------------- phase A: alive flags + (rare) exact W --------------------
// grid = 64 row-blocks x 4 rule-groups = 256 blocks, 256 thr (4 waves).
// wave <-> one 16-rule flag word; processes rules in 4 groups of 4.
__global__ __launch_bounds__(256) void w_kernel(
    const float*  __restrict__ x,       // [BATCH][IN_DIM]
    const float4* __restrict__ Antes,   // [N_RULES][IN_DIM] (a,b,c,d)
    float* __restrict__ W,              // [N_RULES][BATCH] (fired entries only)
    unsigned* __restrict__ flags)       // [64][16]: word r>>4, bit r&15
{
    __shared__ float xs[IN_DIM][65];    // [i][row], padded

    int tid  = threadIdx.x;
    int nblk = blockIdx.x & 63;
    int rgrp = blockIdx.x >> 6;         // 0..3 (64 rules each)
    int n0   = nblk * 64;

    // stage 64x64 x-tile: float4 global loads, padded LDS writes
    #pragma unroll
    for (int k = 0; k < 4; ++k) {
        int flat = tid + k * 256;       // 0..1023 float4s
        int nl = flat >> 4;
        int i4 = (flat & 15) * 4;
        float4 v = *reinterpret_cast<const float4*>(x + (n0 + nl) * IN_DIM + i4);
        xs[i4 + 0][nl] = v.x;
        xs[i4 + 1][nl] = v.y;
        xs[i4 + 2][nl] = v.z;
        xs[i4 + 3][nl] = v.w;
    }
    __syncthreads();

    int lane = tid & 63;                // = row within block
    int wvu  = __builtin_amdgcn_readfirstlane(tid >> 6);
    int r0   = rgrp * 64 + wvu * 16;    // this wave's 16 rules

    unsigned mask = 0;
    for (int g = 0; g < 4; ++g) {
        int rb4 = r0 + g * 4;
        const float4* __restrict__ ap = Antes + rb4 * IN_DIM;

        float m[4] = {1e30f, 1e30f, 1e30f, 1e30f};
        for (int ib = 0; ib < IN_DIM; ib += 8) {
            #pragma unroll
            for (int io = 0; io < 8; ++io) {
                int i = ib + io;
                float xv = xs[i][lane];
                #pragma unroll
                for (int rr = 0; rr < 4; ++rr) {
                    float4 q = ap[rr * IN_DIM + i];     // uniform -> s_load
                    // sign-only membership bound: min(x-a, d-x)
                    m[rr] = fminf(m[rr], fminf(xv - q.x, q.w - xv));
                }
            }
            float mx = fmaxf(fmaxf(m[0], m[1]), fmaxf(m[2], m[3]));
            if (!__any(mx > 0.0f)) break;   // exact: min is non-increasing
        }

        unsigned gf = 0;
        #pragma unroll
        for (int rr = 0; rr < 4; ++rr)
            if (__any(m[rr] > 0.0f)) gf |= 1u << rr;

        if (gf) {                       // rare: compute exact w, store
            for (int rr = 0; rr < 4; ++rr) {
                if (!(gf & (1u << rr))) continue;
                const float4* __restrict__ aq = ap + rr * IN_DIM;
                float wm = 1e30f;
                for (int i = 0; i < IN_DIM; ++i) {
                    float4 q = aq[i];
                    float iba = 1.0f / (q.y - q.x + EPS_TRAP);
                    float idc = 1.0f / (q.w - q.z + EPS_TRAP);
                    float xv = xs[i][lane];
                    wm = fminf(wm, fminf((xv - q.x) * iba, (q.w - xv) * idc));
                }
                float w = fminf(fmaxf(wm, 0.0f), 1.0f);
                W[(rb4 + rr) * BATCH + n0 + lane] = w;
            }
        }
        mask |= gf << (g * 4);
    }
    if (lane == 0) flags[nblk * 16 + rgrp * 4 + wvu] = mask;
}

// ---------------- phase B: flag-gated combine ------------------------------
// grid = 256 blocks x 256 thr (4 waves); block = 16 batch rows.
// Zero path (universal here): one float4 store per thread.
__global__ __launch_bounds__(256) void combine_kernel(
    const float*  __restrict__ W,       // [N_RULES][BATCH]
    const float4* __restrict__ Cons,    // [N_RULES][OUT_DIM]
    const unsigned* __restrict__ flags, // [64][16]
    float* __restrict__ out)            // [BATCH][OUT_DIM]
{
    __shared__ unsigned fw[16];
    __shared__ float lN[4][16][64];
    __shared__ float lD[4][16][64];

    int tid   = threadIdx.x;
    int nbase = blockIdx.x * 16;
    int nblk  = blockIdx.x >> 2;        // 64-row flag block

    if (tid < 16) fw[tid] = flags[nblk * 16 + tid];
    __syncthreads();

    unsigned any = 0;
    #pragma unroll
    for (int i = 0; i < 16; ++i) any |= fw[i];

    if (any == 0u) {                    // all 256 rules dead for these rows
        reinterpret_cast<float4*>(out)[blockIdx.x * 256 + tid] =
            make_float4(0.f, 0.f, 0.f, 0.f);
        return;
    }

    // ---- rare fired path ----
    int lane = tid & 63;                // output dim j
    int wv   = __builtin_amdgcn_readfirstlane(tid >> 6);    // rule chunk of 64

    unsigned long long mask =
        (unsigned long long)fw[wv * 4 + 0]        |
        ((unsigned long long)fw[wv * 4 + 1] << 16) |
        ((unsigned long long)fw[wv * 4 + 2] << 32) |
        ((unsigned long long)fw[wv * 4 + 3] << 48);
    int rbase = wv * 64;

    float num[16], den[16];
    #pragma unroll
    for (int k = 0; k < 16; ++k) { num[k] = 0.0f; den[k] = 0.0f; }

    while (mask) {
        int lr = __ffsll(mask) - 1;
        mask &= mask - 1;
        int r = rbase + lr;

        float4 c = Cons[r * OUT_DIM + lane];
        float A = c.x, B = c.y, C = c.z, D = c.w;
        float c1 = 3.0f * (D * D - A * A);
        float c2 = 3.0f * (C * D - A * B) - c1;
        float c3 = (C - D + A - B) * (C - D - A + B);
        float d1 = 2.0f * (D - A);
        float d2 = C + A - D - B;

        const float* __restrict__ wp = W + r * BATCH + nbase;   // uniform
        #pragma unroll
        for (int k = 0; k < 16; ++k) {
            float w = wp[k];                    // s_load
            float tn = fmaf(fmaf(c3, w, c2), w, c1);
            num[k] = fmaf(tn, w, num[k]);
            den[k] = fmaf(fmaf(d2, w, d1), w, den[k]);
        }
    }

    #pragma unroll
    for (int k = 0; k < 16; ++k) { lN[wv][k][lane] = num[k]; lD[wv][k][lane] = den[k]; }
    __syncthreads();

    #pragma unroll
    for (int kk = 0; kk < 4; ++kk) {
        int row = (tid >> 6) * 4 + kk;
        float n = lN[0][row][lane] + lN[1][row][lane] +
                  lN[2][row][lane] + lN[3][row][lane];
        float d = lD[0][row][lane] + lD[1][row][lane] +
                  lD[2][row][lane] + lD[3][row][lane];
        d += (float)N_RULES * EPS_F32;
        out[(nbase + row) * OUT_DIM + lane] = (d != 0.0f) ? (n / d) * (1.0f / 3.0f) : 0.0f;
    }
}

// ---------------- fallback: fully fused, no workspace (known-correct) ------
__global__ __launch_bounds__(256) void fused_kernel(
    const float*  __restrict__ x,
    const float4* __restrict__ Antes,
    const float4* __restrict__ Cons,
    float* __restrict__ out)
{
    __shared__ float xs[IN_DIM][9];
    __shared__ float wl[N_RULES][9];

    int n0 = blockIdx.x * 8;
    int t  = threadIdx.x;

    for (int k = 0; k < 2; ++k) {
        int idx = t * 2 + k;
        int nl = idx >> 6, i = idx & 63;
        xs[i][nl] = x[(n0 + nl) * IN_DIM + i];
    }
    __syncthreads();

    {
        float wmin[8];
        #pragma unroll
        for (int n = 0; n < 8; ++n) wmin[n] = 1e30f;
        const float4* ap = Antes + t * IN_DIM;
        for (int i = 0; i < IN_DIM; ++i) {
            float4 q = ap[i];
            float iba = 1.0f / (q.y - q.x + EPS_TRAP);
            float idc = 1.0f / (q.w - q.z + EPS_TRAP);
            float na = -q.x * iba, dq = q.w * idc;
            #pragma unroll
            for (int n = 0; n < 8; ++n) {
                float xv = xs[i][n];
                float y = fminf(fmaf(xv, iba, na), fmaf(xv, -idc, dq));
                y = fminf(fmaxf(y, 0.0f), 1.0f);
                wmin[n] = fminf(wmin[n], y);
            }
        }
        #pragma unroll
        for (int n = 0; n < 8; ++n) wl[t][n] = wmin[n];
    }
    __syncthreads();

    int lane = t & 63, wv = t >> 6;
    float num0 = 0.f, den0 = 0.f, num1 = 0.f, den1 = 0.f;
    for (int r = 0; r < N_RULES; ++r) {
        float4 c = Cons[r * OUT_DIM + lane];
        float A = c.x, B = c.y, C = c.z, D = c.w;
        float c1 = 3.0f * (D * D - A * A);
        float c2 = 3.0f * (C * D - A * B) - c1;
        float c3 = (C - D + A - B) * (C - D - A + B);
        float d1 = 2.0f * (D - A);
        float d2 = C + A - D - B;
        float wa = wl[r][wv * 2], wb = wl[r][wv * 2 + 1];
        float wa2 = wa * wa, wa3 = wa2 * wa;
        float wb2 = wb * wb, wb3 = wb2 * wb;
        num0 = fmaf(c1, wa, num0); num0 = fmaf(c2, wa2, num0); num0 = fmaf(c3, wa3, num0);
        den0 = fmaf(d1, wa, den0); den0 = fmaf(d2, wa2, den0);
        num1 = fmaf(c1, wb, num1); num1 = fmaf(c2, wb2, num1); num1 = fmaf(c3, wb3, num1);
        den1 = fmaf(d1, wb, den1); den1 = fmaf(d2, wb2, den1);
    }
    den0 += 256.0f * EPS_F32;
    den1 += 256.0f * EPS_F32;
    float y0 = (den0 != 0.0f) ? num0 / den0 : 0.0f;
    float y1 = (den1 != 0.0f) ? num1 / den1 : 0.0f;
    out[(n0 + wv * 2) * OUT_DIM + lane]     = y0 * (1.0f / 3.0f);
    out[(n0 + wv * 2 + 1) * OUT_DIM + lane] = y1 * (1.0f / 3.0f);
}

extern "C" void kernel_launch(void* const* d_in, const int* in_sizes, int n_in,
                              void* d_out, int out_size, void* d_ws, size_t ws_size,
                              hipStream_t stream) {
    const float* x     = (const float*)d_in[0];
    const float* Antes = (const float*)d_in[1];
    const float* Cons  = (const float*)d_in[2];
    float* out = (float*)d_out;

    const size_t W_BYTES  = (size_t)N_RULES * BATCH * 4;    // 4 MiB
    const size_t FL_BYTES = 64 * 16 * sizeof(unsigned);     // 4 KiB
    const size_t NEED = W_BYTES + FL_BYTES;

    if (ws_size >= NEED) {
        char* p = (char*)d_ws;
        float*    Wp    = (float*)p;      p += W_BYTES;
        unsigned* flags = (unsigned*)p;

        w_kernel<<<256, 256, 0, stream>>>(x, (const float4*)Antes, Wp, flags);
        combine_kernel<<<256, 256, 0, stream>>>(Wp, (const float4*)Cons, flags, out);
    } else {
        fused_kernel<<<512, 256, 0, stream>>>(x, (const float4*)Antes,
                                              (const float4*)Cons, out);
    }
}